// Round 1
// baseline (16765.350 us; speedup 1.0000x reference)
//
#include <hip/hip_runtime.h>

typedef __bf16 bf16x8 __attribute__((ext_vector_type(8)));
typedef float f32x4 __attribute__((ext_vector_type(4)));
typedef unsigned short u16;

constexpr int T = 256, B = 64, D = 512, H = 1024;
constexpr int G4 = 4 * H;
constexpr int NBLK = 128;   // 64 blocks layer0 + 64 blocks layer1
constexpr int NTHR = 256;   // 4 waves; wave = one 16-batch M-tile

// ---- workspace layout (bytes) ----
constexpr size_t OFF_WX0 = 0;                                   // Wih0 bf16 [4096][512]
constexpr size_t OFF_WH0 = OFF_WX0 + (size_t)G4 * D * 2;        // Whh0 bf16 [4096][1024]
constexpr size_t OFF_WX1 = OFF_WH0 + (size_t)G4 * H * 2;        // Wih1 bf16 [4096][1024]
constexpr size_t OFF_WH1 = OFF_WX1 + (size_t)G4 * H * 2;        // Whh1 bf16 [4096][1024]
constexpr size_t OFF_XIN = OFF_WH1 + (size_t)G4 * H * 2;        // input bf16 [T][B][D]
constexpr size_t OFF_XS1 = OFF_XIN + (size_t)T * B * D * 2;     // h0-out ring bf16 [4][B][H]
constexpr size_t OFF_H1B = OFF_XS1 + (size_t)4 * B * H * 2;     // h1 state bf16 [2][B][H]
constexpr size_t OFF_B0  = OFF_H1B + (size_t)2 * B * H * 2;     // bias0 f32 [4096]
constexpr size_t OFF_B1  = OFF_B0 + (size_t)G4 * 4;             // bias1 f32 [4096]
constexpr size_t OFF_BAR = OFF_B1 + (size_t)G4 * 4;             // barrier counter u32

__device__ __forceinline__ u16 f2bf(float f) {
  unsigned u = __builtin_bit_cast(unsigned, f);
  u += 0x7fffu + ((u >> 16) & 1u);
  return (u16)(u >> 16);
}

__device__ __forceinline__ bf16x8 load16(const u16* p) {
  return __builtin_bit_cast(bf16x8, *reinterpret_cast<const uint4*>(p));
}

__device__ __forceinline__ f32x4 mfma16(bf16x8 a, bf16x8 b, f32x4 c) {
  return __builtin_amdgcn_mfma_f32_16x16x32_bf16(a, b, c, 0, 0, 0);
}

__device__ __forceinline__ float sigm(float x) { return 1.f / (1.f + expf(-x)); }

// ---------------- prep kernels ----------------
__global__ void cvt_bf16(const float* __restrict__ src, u16* __restrict__ dst, int n4) {
  int i = blockIdx.x * blockDim.x + threadIdx.x;
  int st = gridDim.x * blockDim.x;
  for (; i < n4; i += st) {
    float4 v = reinterpret_cast<const float4*>(src)[i];
    ushort4 o;
    o.x = f2bf(v.x); o.y = f2bf(v.y); o.z = f2bf(v.z); o.w = f2bf(v.w);
    reinterpret_cast<ushort4*>(dst)[i] = o;
  }
}

__global__ void init_state(const float* __restrict__ h0,
                           u16* __restrict__ xs1, u16* __restrict__ h1buf,
                           const float* __restrict__ bih0, const float* __restrict__ bhh0,
                           const float* __restrict__ bih1, const float* __restrict__ bhh1,
                           float* __restrict__ bias0, float* __restrict__ bias1,
                           unsigned* __restrict__ bar) {
  int i = blockIdx.x * blockDim.x + threadIdx.x;
  if (i == 0) *bar = 0u;
  if (i < 2 * B * H) {
    int l = i / (B * H), rem = i % (B * H);
    int b = rem / H, k = rem % H;
    u16 v = f2bf(h0[(size_t)b * 2 * H + (size_t)l * H + k]);
    if (l == 0) xs1[(size_t)b * H + k] = v;   // ring slot 0 = initial h for layer0
    else        h1buf[(size_t)b * H + k] = v; // parity 0 = initial h for layer1
  }
  if (i < G4) {
    bias0[i] = bih0[i] + bhh0[i];
    bias1[i] = bih1[i] + bhh1[i];
  }
}

// ---------------- persistent pipelined LSTM ----------------
__global__ void __launch_bounds__(NTHR) lstm_seq(
    const u16* __restrict__ xin,
    const u16* __restrict__ wx0, const u16* __restrict__ wh0,
    const u16* __restrict__ wx1, const u16* __restrict__ wh1,
    const float* __restrict__ bias0, const float* __restrict__ bias1,
    u16* __restrict__ xs1, u16* __restrict__ h1buf,
    const float* __restrict__ c0, const int* __restrict__ reset,
    float* __restrict__ out, unsigned* __restrict__ bar) {
  const int group = blockIdx.x >> 6;   // 0 = layer0, 1 = layer1
  const int blk   = blockIdx.x & 63;
  const int hcol0 = blk * 16;          // 16 h-columns per block
  const int wave  = threadIdx.x >> 6;  // M-tile index (16 batches each)
  const int lane  = threadIdx.x & 63;
  const int quad  = lane >> 4;
  const int ln    = lane & 15;
  const int brow0 = wave * 16;
  const int arow  = brow0 + ln;        // batch row this lane loads for A-frags
  const int col   = hcol0 + ln;        // h-column of this lane's accumulators
  const int bc0   = brow0 + quad * 4;  // first batch of this lane's D rows

  const u16* wx = group ? wx1 : wx0;
  const u16* wh = group ? wh1 : wh0;
  const float* bias = group ? bias1 : bias0;
  const int KX = group ? H : D;

  const size_t BH = (size_t)B * H;
  const size_t OUT_HN = (size_t)T * BH;
  const size_t OUT_CN = OUT_HN + 2 * BH;

  float creg[4];
#pragma unroll
  for (int r = 0; r < 4; ++r)
    creg[r] = c0[(size_t)(bc0 + r) * 2 * H + (size_t)group * H + col];

  float bval[4];
  const u16* wxr[4];
  const u16* whr[4];
#pragma unroll
  for (int g = 0; g < 4; ++g) {
    int j = g * H + col;               // gate order: i, f, g, o
    bval[g] = bias[j];
    wxr[g] = wx + (size_t)j * KX + quad * 8;
    whr[g] = wh + (size_t)j * H + quad * 8;
  }

  const bf16x8 zero8 = __builtin_bit_cast(bf16x8, make_uint4(0u, 0u, 0u, 0u));

  for (int s = 0; s <= T; ++s) {
    const bool active = (group == 0) ? (s < T) : (s >= 1);
    if (active) {
      const int t = (group == 0) ? s : s - 1;
      f32x4 acc[4];
#pragma unroll
      for (int g = 0; g < 4; ++g) acc[g] = (f32x4){bval[g], bval[g], bval[g], bval[g]};

      const int rstA = reset[t * B + arow];  // reset applies to recurrent state only

      // ---- x part: layer0 reads input[t], layer1 reads h0-out(t) (ring slot (t+1)&3)
      const u16* abase = (group == 0)
          ? xin + (size_t)t * B * D + (size_t)arow * D + quad * 8
          : xs1 + (size_t)((t + 1) & 3) * BH + (size_t)arow * H + quad * 8;
      {
        const int ks = KX >> 5;
#pragma unroll 4
        for (int kc = 0; kc < ks; ++kc) {
          const int o = kc << 5;
          bf16x8 av = load16(abase + o);
          acc[0] = mfma16(av, load16(wxr[0] + o), acc[0]);
          acc[1] = mfma16(av, load16(wxr[1] + o), acc[1]);
          acc[2] = mfma16(av, load16(wxr[2] + o), acc[2]);
          acc[3] = mfma16(av, load16(wxr[3] + o), acc[3]);
        }
      }
      // ---- h part: recurrent state, zeroed per-batch when reset
      const u16* hbase = (group == 0)
          ? xs1 + (size_t)(t & 3) * BH + (size_t)arow * H + quad * 8
          : h1buf + (size_t)(t & 1) * BH + (size_t)arow * H + quad * 8;
      {
#pragma unroll 4
        for (int kc = 0; kc < (H >> 5); ++kc) {
          const int o = kc << 5;
          bf16x8 av = rstA ? zero8 : load16(hbase + o);
          acc[0] = mfma16(av, load16(whr[0] + o), acc[0]);
          acc[1] = mfma16(av, load16(whr[1] + o), acc[1]);
          acc[2] = mfma16(av, load16(whr[2] + o), acc[2]);
          acc[3] = mfma16(av, load16(whr[3] + o), acc[3]);
        }
      }
      // ---- cell update (register-local: D row r -> batch bc0+r, column col)
#pragma unroll
      for (int r = 0; r < 4; ++r) {
        const int b = bc0 + r;
        const int rst = reset[t * B + b];
        float cp = rst ? 0.f : creg[r];
        float i_ = sigm(acc[0][r]);
        float f_ = sigm(acc[1][r]);
        float g_ = tanhf(acc[2][r]);
        float o_ = sigm(acc[3][r]);
        float cn = fmaf(f_, cp, i_ * g_);
        float hn = o_ * tanhf(cn);
        creg[r] = cn;
        u16 hb = f2bf(hn);
        if (group == 0) {
          xs1[(size_t)((t + 1) & 3) * BH + (size_t)b * H + col] = hb;
          if (t == T - 1) {
            out[OUT_HN + (size_t)b * 2 * H + col] = hn;
            out[OUT_CN + (size_t)b * 2 * H + col] = cn;
          }
        } else {
          h1buf[(size_t)((t + 1) & 1) * BH + (size_t)b * H + col] = hb;
          out[(size_t)t * BH + (size_t)b * H + col] = hn;
          if (t == T - 1) {
            out[OUT_HN + (size_t)b * 2 * H + H + col] = hn;
            out[OUT_CN + (size_t)b * 2 * H + H + col] = cn;
          }
        }
      }
    }

    // ---- grid barrier (monotonic counter; all 128 blocks arrive every slot)
    if (s < T) {
      __syncthreads();
      __threadfence();  // release: publish xs1/h1buf writes device-wide
      if (threadIdx.x == 0) {
        atomicAdd(bar, 1u);
        const unsigned target = (unsigned)(s + 1) * NBLK;
        while (__hip_atomic_load(bar, __ATOMIC_ACQUIRE, __HIP_MEMORY_SCOPE_AGENT) < target) {
          __builtin_amdgcn_s_sleep(2);
        }
      }
      __syncthreads();
      __threadfence();  // acquire: invalidate stale L1/L2 before reading peers' data
    }
  }
}

extern "C" void kernel_launch(void* const* d_in, const int* in_sizes, int n_in,
                              void* d_out, int out_size, void* d_ws, size_t ws_size,
                              hipStream_t stream) {
  (void)in_sizes; (void)n_in; (void)out_size; (void)ws_size;
  const float* input = (const float*)d_in[0];
  const int*   reset = (const int*)d_in[1];
  const float* h0    = (const float*)d_in[2];
  const float* c0    = (const float*)d_in[3];
  const float* Wih0  = (const float*)d_in[4];
  const float* Whh0  = (const float*)d_in[5];
  const float* bih0  = (const float*)d_in[6];
  const float* bhh0  = (const float*)d_in[7];
  const float* Wih1  = (const float*)d_in[8];
  const float* Whh1  = (const float*)d_in[9];
  const float* bih1  = (const float*)d_in[10];
  const float* bhh1  = (const float*)d_in[11];
  float* out = (float*)d_out;
  char* ws = (char*)d_ws;

  u16* wx0 = (u16*)(ws + OFF_WX0);
  u16* wh0 = (u16*)(ws + OFF_WH0);
  u16* wx1 = (u16*)(ws + OFF_WX1);
  u16* wh1 = (u16*)(ws + OFF_WH1);
  u16* xin = (u16*)(ws + OFF_XIN);
  u16* xs1 = (u16*)(ws + OFF_XS1);
  u16* h1b = (u16*)(ws + OFF_H1B);
  float* pb0 = (float*)(ws + OFF_B0);
  float* pb1 = (float*)(ws + OFF_B1);
  unsigned* bar = (unsigned*)(ws + OFF_BAR);

  cvt_bf16<<<1024, 256, 0, stream>>>(Wih0, wx0, G4 * D / 4);
  cvt_bf16<<<1024, 256, 0, stream>>>(Whh0, wh0, G4 * H / 4);
  cvt_bf16<<<1024, 256, 0, stream>>>(Wih1, wx1, G4 * H / 4);
  cvt_bf16<<<1024, 256, 0, stream>>>(Whh1, wh1, G4 * H / 4);
  cvt_bf16<<<2048, 256, 0, stream>>>(input, xin, T * B * D / 4);
  init_state<<<512, 256, 0, stream>>>(h0, xs1, h1b, bih0, bhh0, bih1, bhh1, pb0, pb1, bar);
  lstm_seq<<<NBLK, NTHR, 0, stream>>>(xin, wx0, wh0, wx1, wh1, pb0, pb1,
                                      xs1, h1b, c0, reset, out, bar);
}

// Round 3
// 8070.641 us; speedup vs baseline: 2.0773x; 2.0773x over previous
//
#include <hip/hip_runtime.h>

typedef __bf16 bf16x8 __attribute__((ext_vector_type(8)));
typedef float f32x4 __attribute__((ext_vector_type(4)));
typedef unsigned short u16;
typedef unsigned long long u64;

constexpr int T = 256, B = 64, D = 512, H = 1024;
constexpr int G4 = 4 * H;
constexpr int NBLK = 128;   // 64 blocks layer0 + 64 blocks layer1
constexpr int NTHR = 512;   // 8 waves = 8 K-octants

// ---- workspace layout (bytes) ----
constexpr size_t OFF_WX0 = 0;                                   // Wih0 bf16 [4096][512]
constexpr size_t OFF_WH0 = OFF_WX0 + (size_t)G4 * D * 2;        // Whh0 bf16 [4096][1024]
constexpr size_t OFF_WX1 = OFF_WH0 + (size_t)G4 * H * 2;        // Wih1 bf16 [4096][1024]
constexpr size_t OFF_WH1 = OFF_WX1 + (size_t)G4 * H * 2;        // Whh1 bf16 [4096][1024]
constexpr size_t OFF_XIN = OFF_WH1 + (size_t)G4 * H * 2;        // input bf16 [T][B][D]
constexpr size_t OFF_XS1 = OFF_XIN + (size_t)T * B * D * 2;     // h0-out ring bf16 [4][B][H]
constexpr size_t OFF_H1B = OFF_XS1 + (size_t)4 * B * H * 2;     // h1 state bf16 [2][B][H]
constexpr size_t OFF_B0  = OFF_H1B + (size_t)2 * B * H * 2;     // bias0 f32 [4096]
constexpr size_t OFF_B1  = OFF_B0 + (size_t)G4 * 4;             // bias1 f32 [4096]
constexpr size_t OFF_BAR = OFF_B1 + (size_t)G4 * 4;             // barrier counter u32

__device__ __forceinline__ u16 f2bf(float f) {
  unsigned u = __builtin_bit_cast(unsigned, f);
  u += 0x7fffu + ((u >> 16) & 1u);
  return (u16)(u >> 16);
}

__device__ __forceinline__ bf16x8 load16(const u16* p) {
  return __builtin_bit_cast(bf16x8, *reinterpret_cast<const uint4*>(p));
}

// system-scope (LLC-coherent, bypasses L1/L2) 16B activation load as 2x8B atomics
__device__ __forceinline__ bf16x8 sysload16(const u16* p) {
  u64 a = __hip_atomic_load((const u64*)p, __ATOMIC_RELAXED, __HIP_MEMORY_SCOPE_SYSTEM);
  u64 b = __hip_atomic_load((const u64*)p + 1, __ATOMIC_RELAXED, __HIP_MEMORY_SCOPE_SYSTEM);
  ulonglong2 v; v.x = a; v.y = b;
  return __builtin_bit_cast(bf16x8, v);
}

__device__ __forceinline__ void sysstore8(u16* p, u64 v) {
  __hip_atomic_store((u64*)p, v, __ATOMIC_RELAXED, __HIP_MEMORY_SCOPE_SYSTEM);
}

__device__ __forceinline__ f32x4 mfma16(bf16x8 a, bf16x8 b, f32x4 c) {
  return __builtin_amdgcn_mfma_f32_16x16x32_bf16(a, b, c, 0, 0, 0);
}

__device__ __forceinline__ float sigm(float x) { return 1.f / (1.f + expf(-x)); }

// ---------------- prep kernels ----------------
__global__ void cvt_bf16(const float* __restrict__ src, u16* __restrict__ dst, int n4) {
  int i = blockIdx.x * blockDim.x + threadIdx.x;
  int st = gridDim.x * blockDim.x;
  for (; i < n4; i += st) {
    float4 v = reinterpret_cast<const float4*>(src)[i];
    ushort4 o;
    o.x = f2bf(v.x); o.y = f2bf(v.y); o.z = f2bf(v.z); o.w = f2bf(v.w);
    reinterpret_cast<ushort4*>(dst)[i] = o;
  }
}

__global__ void init_state(const float* __restrict__ h0,
                           u16* __restrict__ xs1, u16* __restrict__ h1buf,
                           const float* __restrict__ bih0, const float* __restrict__ bhh0,
                           const float* __restrict__ bih1, const float* __restrict__ bhh1,
                           float* __restrict__ bias0, float* __restrict__ bias1,
                           unsigned* __restrict__ bar) {
  int i = blockIdx.x * blockDim.x + threadIdx.x;
  if (i == 0) *bar = 0u;
  if (i < 2 * B * H) {
    int l = i / (B * H), rem = i % (B * H);
    int b = rem / H, k = rem % H;
    u16 v = f2bf(h0[(size_t)b * 2 * H + (size_t)l * H + k]);
    if (l == 0) xs1[(size_t)b * H + k] = v;   // ring slot 0 = initial h for layer0
    else        h1buf[(size_t)b * H + k] = v; // parity 0 = initial h for layer1
  }
  if (i < G4) {
    bias0[i] = bih0[i] + bhh0[i];
    bias1[i] = bih1[i] + bhh1[i];
  }
}

// ---------------- persistent pipelined LSTM, register-resident weights ----------------
template <int L>
__device__ __forceinline__ void run_layer(
    const u16* __restrict__ xin, const u16* __restrict__ wx, const u16* __restrict__ wh,
    const float* __restrict__ bias, u16* __restrict__ xs1, u16* __restrict__ h1b,
    const float* __restrict__ c0, const int* __restrict__ reset,
    float* __restrict__ out, unsigned* __restrict__ bar, int col0,
    float* __restrict__ red /* shared, 8*4*1024 floats */) {
  constexpr int KX  = L ? H : D;      // x-part K
  constexpr int NCX = KX / 32;        // x chunks (32 or 16)
  constexpr int NC  = NCX + H / 32;   // total K chunks (64 or 48)
  constexpr int CPW = NC / 8;         // chunks per wave (8 or 6)
  const size_t BH = (size_t)B * H;
  const size_t OUT_HN = (size_t)T * BH;
  const size_t OUT_CN = OUT_HN + 2 * BH;

  const int tid  = threadIdx.x;
  const int wave = tid >> 6;
  const int lane = tid & 63;
  const int q    = lane >> 4;
  const int ln   = lane & 15;
  const int c0i  = wave * CPW;

  // ---- preload this wave's weight fragments into registers (held for all T steps)
  bf16x8 wreg[4][CPW];
#pragma unroll
  for (int g = 0; g < 4; ++g)
#pragma unroll
    for (int cc = 0; cc < CPW; ++cc) {
      const int c = c0i + cc;
      const u16* W = (c < NCX) ? wx : wh;
      const int stride = (c < NCX) ? KX : H;
      const int kk = ((c < NCX) ? c : c - NCX) * 32 + q * 8;
      wreg[g][cc] = load16(W + (size_t)(g * H + col0 + ln) * stride + kk);
    }

  // ---- cell-update thread state (threads 0..255: 4 cells each)
  const int cb   = tid >> 2;             // batch
  const int ccol = col0 + (tid & 3) * 4; // first of 4 columns
  float creg[4];
  f32x4 biasv[4];
  if (tid < 256) {
#pragma unroll
    for (int j = 0; j < 4; ++j)
      creg[j] = c0[(size_t)cb * 2 * H + (size_t)L * H + ccol + j];
#pragma unroll
    for (int g = 0; g < 4; ++g)
      biasv[g] = *reinterpret_cast<const f32x4*>(&bias[g * H + ccol]);
  }

  const bf16x8 zero8 = __builtin_bit_cast(bf16x8, make_uint4(0u, 0u, 0u, 0u));

  for (int s = 0; s <= T; ++s) {
    const bool active = (L == 0) ? (s < T) : (s >= 1);
    if (active) {
      const int t = (L == 0) ? s : s - 1;

      f32x4 acc[4][4];
#pragma unroll
      for (int g = 0; g < 4; ++g)
#pragma unroll
        for (int m = 0; m < 4; ++m) acc[g][m] = (f32x4){0.f, 0.f, 0.f, 0.f};

      int rz[4];
#pragma unroll
      for (int m = 0; m < 4; ++m) rz[m] = reset[t * B + 16 * m + ln];

      const u16* xsrc;
      if constexpr (L == 0) xsrc = xin + (size_t)t * B * D;
      else                  xsrc = xs1 + (size_t)((t + 1) & 3) * BH;
      const u16* hsrc = (L == 0) ? xs1 + (size_t)(t & 3) * BH
                                 : h1b + (size_t)(t & 1) * BH;

#pragma unroll
      for (int cc = 0; cc < CPW; ++cc) {
        const int c = c0i + cc;
        bf16x8 frag[4];
        if (c < NCX) {
          const int kk = c * 32 + q * 8;
          if constexpr (L == 0) {
#pragma unroll
            for (int m = 0; m < 4; ++m)
              frag[m] = load16(xsrc + (size_t)(16 * m + ln) * KX + kk);
          } else {
#pragma unroll
            for (int m = 0; m < 4; ++m)
              frag[m] = sysload16(xsrc + (size_t)(16 * m + ln) * H + kk);
          }
        } else {
          const int kk = (c - NCX) * 32 + q * 8;
#pragma unroll
          for (int m = 0; m < 4; ++m) {
            bf16x8 v = sysload16(hsrc + (size_t)(16 * m + ln) * H + kk);
            frag[m] = rz[m] ? zero8 : v;
          }
        }
#pragma unroll
        for (int g = 0; g < 4; ++g)
#pragma unroll
          for (int m = 0; m < 4; ++m)
            acc[g][m] = mfma16(frag[m], wreg[g][cc], acc[g][m]);
      }

      // ---- dump K-partials to LDS: cellid = batch*16 + localcol
#pragma unroll
      for (int g = 0; g < 4; ++g)
#pragma unroll
        for (int m = 0; m < 4; ++m) {
          float* pb = &red[((wave * 4 + g) << 10) + ((16 * m + 4 * q) << 4) + ln];
#pragma unroll
          for (int r = 0; r < 4; ++r) pb[r << 4] = acc[g][m][r];
        }
      __syncthreads();

      // ---- reduce + cell update (threads 0..255, 4 cells each)
      if (tid < 256) {
        f32x4 gate[4];
#pragma unroll
        for (int g = 0; g < 4; ++g) {
          f32x4 sum = biasv[g];
#pragma unroll
          for (int w = 0; w < 8; ++w)
            sum += reinterpret_cast<const f32x4*>(red)[((w * 4 + g) << 8) + tid];
          gate[g] = sum;
        }
        const int rst = reset[t * B + cb];
        float hv[4];
        u16 hb[4];
#pragma unroll
        for (int j = 0; j < 4; ++j) {
          float cp = rst ? 0.f : creg[j];
          float i_ = sigm(gate[0][j]);
          float f_ = sigm(gate[1][j]);
          float g_ = tanhf(gate[2][j]);
          float o_ = sigm(gate[3][j]);
          float cn = fmaf(f_, cp, i_ * g_);
          float hn = o_ * tanhf(cn);
          creg[j] = cn;
          hv[j] = hn;
          hb[j] = f2bf(hn);
        }
        u64 hpack = (u64)hb[0] | ((u64)hb[1] << 16) | ((u64)hb[2] << 32) | ((u64)hb[3] << 48);
        u16* hdst = (L == 0)
            ? xs1 + (size_t)((t + 1) & 3) * BH + (size_t)cb * H + ccol
            : h1b + (size_t)((t + 1) & 1) * BH + (size_t)cb * H + ccol;
        sysstore8(hdst, hpack);
        if constexpr (L == 1) {
          *reinterpret_cast<f32x4*>(&out[(size_t)t * BH + (size_t)cb * H + ccol]) =
              (f32x4){hv[0], hv[1], hv[2], hv[3]};
        }
        if (t == T - 1) {
          *reinterpret_cast<f32x4*>(&out[OUT_HN + (size_t)cb * 2 * H + (size_t)L * H + ccol]) =
              (f32x4){hv[0], hv[1], hv[2], hv[3]};
          *reinterpret_cast<f32x4*>(&out[OUT_CN + (size_t)cb * 2 * H + (size_t)L * H + ccol]) =
              (f32x4){creg[0], creg[1], creg[2], creg[3]};
        }
      }
    }

    // ---- grid barrier (monotonic counter; all 128 blocks arrive every slot)
    if (s < T) {
      __syncthreads();   // compiler emits vmcnt(0) drain: system stores are at LLC
      if (tid == 0) {
        __hip_atomic_fetch_add(bar, 1u, __ATOMIC_RELEASE, __HIP_MEMORY_SCOPE_SYSTEM);
        const unsigned target = (unsigned)(s + 1) * NBLK;
        while (__hip_atomic_load(bar, __ATOMIC_ACQUIRE, __HIP_MEMORY_SCOPE_AGENT) < target)
          __builtin_amdgcn_s_sleep(2);
      }
      __syncthreads();
    }
  }
}

__global__ void __launch_bounds__(NTHR, 2) lstm_seq(
    const u16* __restrict__ xin,
    const u16* __restrict__ wx0, const u16* __restrict__ wh0,
    const u16* __restrict__ wx1, const u16* __restrict__ wh1,
    const float* __restrict__ bias0, const float* __restrict__ bias1,
    u16* __restrict__ xs1, u16* __restrict__ h1b,
    const float* __restrict__ c0, const int* __restrict__ reset,
    float* __restrict__ out, unsigned* __restrict__ bar) {
  __shared__ float red[8 * 4 * 1024];   // 128 KB, shared by both instantiations
  const int group = blockIdx.x >> 6;
  const int col0 = (blockIdx.x & 63) << 4;
  if (group == 0)
    run_layer<0>(xin, wx0, wh0, bias0, xs1, h1b, c0, reset, out, bar, col0, red);
  else
    run_layer<1>(nullptr, wx1, wh1, bias1, xs1, h1b, c0, reset, out, bar, col0, red);
}

extern "C" void kernel_launch(void* const* d_in, const int* in_sizes, int n_in,
                              void* d_out, int out_size, void* d_ws, size_t ws_size,
                              hipStream_t stream) {
  (void)in_sizes; (void)n_in; (void)out_size; (void)ws_size;
  const float* input = (const float*)d_in[0];
  const int*   reset = (const int*)d_in[1];
  const float* h0    = (const float*)d_in[2];
  const float* c0    = (const float*)d_in[3];
  const float* Wih0  = (const float*)d_in[4];
  const float* Whh0  = (const float*)d_in[5];
  const float* bih0  = (const float*)d_in[6];
  const float* bhh0  = (const float*)d_in[7];
  const float* Wih1  = (const float*)d_in[8];
  const float* Whh1  = (const float*)d_in[9];
  const float* bih1  = (const float*)d_in[10];
  const float* bhh1  = (const float*)d_in[11];
  float* out = (float*)d_out;
  char* ws = (char*)d_ws;

  u16* wx0 = (u16*)(ws + OFF_WX0);
  u16* wh0 = (u16*)(ws + OFF_WH0);
  u16* wx1 = (u16*)(ws + OFF_WX1);
  u16* wh1 = (u16*)(ws + OFF_WH1);
  u16* xin = (u16*)(ws + OFF_XIN);
  u16* xs1 = (u16*)(ws + OFF_XS1);
  u16* h1b = (u16*)(ws + OFF_H1B);
  float* pb0 = (float*)(ws + OFF_B0);
  float* pb1 = (float*)(ws + OFF_B1);
  unsigned* bar = (unsigned*)(ws + OFF_BAR);

  cvt_bf16<<<1024, 256, 0, stream>>>(Wih0, wx0, G4 * D / 4);
  cvt_bf16<<<1024, 256, 0, stream>>>(Whh0, wh0, G4 * H / 4);
  cvt_bf16<<<1024, 256, 0, stream>>>(Wih1, wx1, G4 * H / 4);
  cvt_bf16<<<1024, 256, 0, stream>>>(Whh1, wh1, G4 * H / 4);
  cvt_bf16<<<2048, 256, 0, stream>>>(input, xin, T * B * D / 4);
  init_state<<<512, 256, 0, stream>>>(h0, xs1, h1b, bih0, bhh0, bih1, bhh1, pb0, pb1, bar);
  lstm_seq<<<NBLK, NTHR, 0, stream>>>(xin, wx0, wh0, wx1, wh1, pb0, pb1,
                                      xs1, h1b, c0, reset, out, bar);
}

// Round 4
// 6561.346 us; speedup vs baseline: 2.5552x; 1.2300x over previous
//
#include <hip/hip_runtime.h>

typedef __bf16 bf16x8 __attribute__((ext_vector_type(8)));
typedef float f32x4 __attribute__((ext_vector_type(4)));
typedef unsigned u32x4 __attribute__((ext_vector_type(4)));
typedef unsigned short u16;
typedef unsigned long long u64;

constexpr int T = 256, B = 64, D = 512, H = 1024;
constexpr int G4 = 4 * H;
constexpr int NBLK = 128;   // 64 blocks layer0 + 64 blocks layer1
constexpr int NTHR = 512;   // 8 waves = 8 K-octants

// ---- workspace layout (bytes) ----
constexpr size_t OFF_WX0 = 0;                                   // Wih0 bf16 [4096][512]
constexpr size_t OFF_WH0 = OFF_WX0 + (size_t)G4 * D * 2;        // Whh0 bf16 [4096][1024]
constexpr size_t OFF_WX1 = OFF_WH0 + (size_t)G4 * H * 2;        // Wih1 bf16 [4096][1024]
constexpr size_t OFF_WH1 = OFF_WX1 + (size_t)G4 * H * 2;        // Whh1 bf16 [4096][1024]
constexpr size_t OFF_XIN = OFF_WH1 + (size_t)G4 * H * 2;        // input bf16 [T][B][D]
constexpr size_t OFF_XS1 = OFF_XIN + (size_t)T * B * D * 2;     // h0-out ring bf16 [4][B][H]
constexpr size_t OFF_H1B = OFF_XS1 + (size_t)4 * B * H * 2;     // h1 state bf16 [2][B][H]
constexpr size_t OFF_B0  = OFF_H1B + (size_t)2 * B * H * 2;     // bias0 f32 [4096]
constexpr size_t OFF_B1  = OFF_B0 + (size_t)G4 * 4;             // bias1 f32 [4096]
constexpr size_t OFF_BAR = OFF_B1 + (size_t)G4 * 4;             // barrier counter u32

__device__ __forceinline__ u16 f2bf(float f) {
  unsigned u = __builtin_bit_cast(unsigned, f);
  u += 0x7fffu + ((u >> 16) & 1u);
  return (u16)(u >> 16);
}

__device__ __forceinline__ bf16x8 load16(const u16* p) {
  return __builtin_bit_cast(bf16x8, *reinterpret_cast<const uint4*>(p));
}

// agent-scope (LLC-coherent, bypasses L1/L2) activation load/store
__device__ __forceinline__ bf16x8 aload16(const u16* p) {
  u64 a = __hip_atomic_load((const u64*)p, __ATOMIC_RELAXED, __HIP_MEMORY_SCOPE_AGENT);
  u64 b = __hip_atomic_load((const u64*)p + 1, __ATOMIC_RELAXED, __HIP_MEMORY_SCOPE_AGENT);
  ulonglong2 v; v.x = a; v.y = b;
  return __builtin_bit_cast(bf16x8, v);
}

__device__ __forceinline__ void astore8(u16* p, u64 v) {
  __hip_atomic_store((u64*)p, v, __ATOMIC_RELAXED, __HIP_MEMORY_SCOPE_AGENT);
}

__device__ __forceinline__ void ntstore4(float* p, f32x4 v) {
  __builtin_nontemporal_store(v, (f32x4*)p);
}

__device__ __forceinline__ f32x4 mfma16(bf16x8 a, bf16x8 b, f32x4 c) {
  return __builtin_amdgcn_mfma_f32_16x16x32_bf16(a, b, c, 0, 0, 0);
}

__device__ __forceinline__ float sigm(float x) { return 1.f / (1.f + expf(-x)); }

// ---------------- prep kernels ----------------
__global__ void cvt_bf16(const float* __restrict__ src, u16* __restrict__ dst, int n4) {
  int i = blockIdx.x * blockDim.x + threadIdx.x;
  int st = gridDim.x * blockDim.x;
  for (; i < n4; i += st) {
    float4 v = reinterpret_cast<const float4*>(src)[i];
    ushort4 o;
    o.x = f2bf(v.x); o.y = f2bf(v.y); o.z = f2bf(v.z); o.w = f2bf(v.w);
    reinterpret_cast<ushort4*>(dst)[i] = o;
  }
}

__global__ void init_state(const float* __restrict__ h0,
                           u16* __restrict__ xs1, u16* __restrict__ h1buf,
                           const float* __restrict__ bih0, const float* __restrict__ bhh0,
                           const float* __restrict__ bih1, const float* __restrict__ bhh1,
                           float* __restrict__ bias0, float* __restrict__ bias1,
                           unsigned* __restrict__ bar) {
  int i = blockIdx.x * blockDim.x + threadIdx.x;
  if (i == 0) *bar = 0u;
  if (i < 2 * B * H) {
    int l = i / (B * H), rem = i % (B * H);
    int b = rem / H, k = rem % H;
    u16 v = f2bf(h0[(size_t)b * 2 * H + (size_t)l * H + k]);
    if (l == 0) xs1[(size_t)b * H + k] = v;   // ring slot 0 = initial h for layer0
    else        h1buf[(size_t)b * H + k] = v; // parity 0 = initial h for layer1
  }
  if (i < G4) {
    bias0[i] = bih0[i] + bhh0[i];
    bias1[i] = bih1[i] + bhh1[i];
  }
}

// ---------------- persistent pipelined LSTM, pinned register weights ----------------
template <int L>
__device__ __forceinline__ void run_layer(
    const u16* __restrict__ xin, const u16* __restrict__ wx, const u16* __restrict__ wh,
    const float* __restrict__ bias, u16* __restrict__ xs1, u16* __restrict__ h1b,
    const float* __restrict__ c0, const int* __restrict__ reset,
    float* __restrict__ out, unsigned* __restrict__ bar, int col0,
    float* __restrict__ red, unsigned* __restrict__ rbits, float* __restrict__ lbias) {
  constexpr int KX  = L ? H : D;      // x-part K
  constexpr int NCX = KX / 32;        // x chunks (16 or 32)
  constexpr int NC  = NCX + H / 32;   // total K chunks (48 or 64)
  constexpr int CPW = NC / 8;         // chunks per wave (6 or 8)
  const size_t BH = (size_t)B * H;
  const size_t OUT_HN = (size_t)T * BH;
  const size_t OUT_CN = OUT_HN + 2 * BH;

  const int tid  = threadIdx.x;
  const int wave = tid >> 6;
  const int lane = tid & 63;
  const int q    = lane >> 4;
  const int ln   = lane & 15;
  const int c0i  = wave * CPW;

  // ---- one-time LDS prep: packed reset bits (2 KB) + this block's bias rows
  for (int w = tid; w < 2 * T; w += NTHR) {
    const int t = w >> 1, half = (w & 1) * 32;
    unsigned v = 0;
#pragma unroll 8
    for (int i = 0; i < 32; ++i) v |= (unsigned)(reset[t * B + half + i] & 1) << i;
    rbits[w] = v;
  }
  if (tid < 64) lbias[tid] = bias[(tid >> 4) * H + col0 + (tid & 15)];

  // ---- preload this wave's weight fragments and PIN them in VGPRs
  u32x4 wreg[4][CPW];
#pragma unroll
  for (int g = 0; g < 4; ++g)
#pragma unroll
    for (int cc = 0; cc < CPW; ++cc) {
      const int c = c0i + cc;
      const u16* W = (c < NCX) ? wx : wh;
      const int stride = (c < NCX) ? KX : H;
      const int kk = ((c < NCX) ? c : c - NCX) * 32 + q * 8;
      wreg[g][cc] = *reinterpret_cast<const u32x4*>(
          W + (size_t)(g * H + col0 + ln) * stride + kk);
    }
#pragma unroll
  for (int g = 0; g < 4; ++g)
#pragma unroll
    for (int cc = 0; cc < CPW; ++cc)
      asm volatile("" : "+v"(wreg[g][cc]));   // opaque: forbids re-load/remat

  // ---- cell-update thread state (threads 0..255: 4 cells each)
  const int cb   = tid >> 2;             // batch
  const int lc4  = (tid & 3) * 4;        // first local col
  float creg[4];
  if (tid < 256) {
#pragma unroll
    for (int j = 0; j < 4; ++j)
      creg[j] = c0[(size_t)cb * 2 * H + (size_t)L * H + col0 + lc4 + j];
  }
  __syncthreads();

  const bf16x8 zero8 = __builtin_bit_cast(bf16x8, make_uint4(0u, 0u, 0u, 0u));

  for (int s = 0; s <= T; ++s) {
    const bool active = (L == 0) ? (s < T) : (s >= 1);
    if (active) {
      const int t = (L == 0) ? s : s - 1;

      f32x4 acc[4][4];
#pragma unroll
      for (int g = 0; g < 4; ++g)
#pragma unroll
        for (int m = 0; m < 4; ++m) acc[g][m] = (f32x4){0.f, 0.f, 0.f, 0.f};

      const unsigned rw0 = rbits[2 * t], rw1 = rbits[2 * t + 1];
      const int rz[4] = {(int)((rw0 >> ln) & 1u), (int)((rw0 >> (16 + ln)) & 1u),
                         (int)((rw1 >> ln) & 1u), (int)((rw1 >> (16 + ln)) & 1u)};

      const u16* xsrc;
      if constexpr (L == 0) xsrc = xin + (size_t)t * B * D;
      else                  xsrc = xs1 + (size_t)((t + 1) & 3) * BH;
      const u16* hsrc = (L == 0) ? xs1 + (size_t)(t & 3) * BH
                                 : h1b + (size_t)(t & 1) * BH;

#pragma unroll
      for (int cc = 0; cc < CPW; ++cc) {
        const int c = c0i + cc;
        bf16x8 frag[4];
        if (c < NCX) {
          const int kk = c * 32 + q * 8;
          if constexpr (L == 0) {
#pragma unroll
            for (int m = 0; m < 4; ++m)
              frag[m] = load16(xsrc + (size_t)(16 * m + ln) * KX + kk);
          } else {
#pragma unroll
            for (int m = 0; m < 4; ++m)
              frag[m] = aload16(xsrc + (size_t)(16 * m + ln) * H + kk);
          }
        } else {
          const int kk = (c - NCX) * 32 + q * 8;
#pragma unroll
          for (int m = 0; m < 4; ++m) {
            bf16x8 v = aload16(hsrc + (size_t)(16 * m + ln) * H + kk);
            frag[m] = rz[m] ? zero8 : v;
          }
        }
#pragma unroll
        for (int g = 0; g < 4; ++g)
#pragma unroll
          for (int m = 0; m < 4; ++m)
            acc[g][m] = mfma16(frag[m], __builtin_bit_cast(bf16x8, wreg[g][cc]), acc[g][m]);
      }

      // ---- dump K-partials to LDS: cellid = batch*16 + localcol
#pragma unroll
      for (int g = 0; g < 4; ++g)
#pragma unroll
        for (int m = 0; m < 4; ++m) {
          float* pb = &red[((wave * 4 + g) << 10) + ((16 * m + 4 * q) << 4) + ln];
#pragma unroll
          for (int r = 0; r < 4; ++r) pb[r << 4] = acc[g][m][r];
        }
      __syncthreads();

      // ---- reduce + cell update (threads 0..255, 4 cells each)
      if (tid < 256) {
        f32x4 gate[4];
#pragma unroll
        for (int g = 0; g < 4; ++g) {
          f32x4 sum = *reinterpret_cast<const f32x4*>(&lbias[g * 16 + lc4]);
#pragma unroll
          for (int w = 0; w < 8; ++w)
            sum += reinterpret_cast<const f32x4*>(red)[((w * 4 + g) << 8) + tid];
          gate[g] = sum;
        }
        const unsigned rwA = rbits[2 * t + (cb >> 5)];
        const int rst = (int)((rwA >> (cb & 31)) & 1u);
        float hv[4];
        u16 hb[4];
#pragma unroll
        for (int j = 0; j < 4; ++j) {
          float cp = rst ? 0.f : creg[j];
          float i_ = sigm(gate[0][j]);
          float f_ = sigm(gate[1][j]);
          float g_ = tanhf(gate[2][j]);
          float o_ = sigm(gate[3][j]);
          float cn = fmaf(f_, cp, i_ * g_);
          float hn = o_ * tanhf(cn);
          creg[j] = cn;
          hv[j] = hn;
          hb[j] = f2bf(hn);
        }
        u64 hpack = (u64)hb[0] | ((u64)hb[1] << 16) | ((u64)hb[2] << 32) | ((u64)hb[3] << 48);
        const int ccol = col0 + lc4;
        u16* hdst = (L == 0)
            ? xs1 + (size_t)((t + 1) & 3) * BH + (size_t)cb * H + ccol
            : h1b + (size_t)((t + 1) & 1) * BH + (size_t)cb * H + ccol;
        astore8(hdst, hpack);
        if constexpr (L == 1) {
          ntstore4(&out[(size_t)t * BH + (size_t)cb * H + ccol],
                   (f32x4){hv[0], hv[1], hv[2], hv[3]});
        }
        if (t == T - 1) {
          ntstore4(&out[OUT_HN + (size_t)cb * 2 * H + (size_t)L * H + ccol],
                   (f32x4){hv[0], hv[1], hv[2], hv[3]});
          ntstore4(&out[OUT_CN + (size_t)cb * 2 * H + (size_t)L * H + ccol],
                   (f32x4){creg[0], creg[1], creg[2], creg[3]});
        }
      }
    }

    // ---- grid barrier: release add, RELAXED spin (no per-poll cache inv!)
    if (s < T) {
      __syncthreads();   // all waves drain their stores (vmcnt) before tid0 signals
      if (tid == 0) {
        __hip_atomic_fetch_add(bar, 1u, __ATOMIC_RELEASE, __HIP_MEMORY_SCOPE_AGENT);
        const unsigned target = (unsigned)(s + 1) * NBLK;
        while (__hip_atomic_load(bar, __ATOMIC_RELAXED, __HIP_MEMORY_SCOPE_AGENT) < target)
          __builtin_amdgcn_s_sleep(4);
      }
      __syncthreads();
      // no acquire fence: all cross-block data is read via L2-bypassing agent
      // atomics (aload16), so L1/L2 never hold stale communicated lines and
      // weights/xin stay L2-resident across steps.
    }
  }
}

__global__ void __launch_bounds__(NTHR, 2) lstm_seq(
    const u16* __restrict__ xin,
    const u16* __restrict__ wx0, const u16* __restrict__ wh0,
    const u16* __restrict__ wx1, const u16* __restrict__ wh1,
    const float* __restrict__ bias0, const float* __restrict__ bias1,
    u16* __restrict__ xs1, u16* __restrict__ h1b,
    const float* __restrict__ c0, const int* __restrict__ reset,
    float* __restrict__ out, unsigned* __restrict__ bar) {
  __shared__ float red[8 * 4 * 1024];     // 128 KB
  __shared__ unsigned rbits[2 * T];       // 2 KB packed reset bits
  __shared__ float lbias[64];             // this block's 64 bias rows
  const int group = blockIdx.x >> 6;
  const int col0 = (blockIdx.x & 63) << 4;
  if (group == 0)
    run_layer<0>(xin, wx0, wh0, bias0, xs1, h1b, c0, reset, out, bar, col0, red, rbits, lbias);
  else
    run_layer<1>(nullptr, wx1, wh1, bias1, xs1, h1b, c0, reset, out, bar, col0, red, rbits, lbias);
}

extern "C" void kernel_launch(void* const* d_in, const int* in_sizes, int n_in,
                              void* d_out, int out_size, void* d_ws, size_t ws_size,
                              hipStream_t stream) {
  (void)in_sizes; (void)n_in; (void)out_size; (void)ws_size;
  const float* input = (const float*)d_in[0];
  const int*   reset = (const int*)d_in[1];
  const float* h0    = (const float*)d_in[2];
  const float* c0    = (const float*)d_in[3];
  const float* Wih0  = (const float*)d_in[4];
  const float* Whh0  = (const float*)d_in[5];
  const float* bih0  = (const float*)d_in[6];
  const float* bhh0  = (const float*)d_in[7];
  const float* Wih1  = (const float*)d_in[8];
  const float* Whh1  = (const float*)d_in[9];
  const float* bih1  = (const float*)d_in[10];
  const float* bhh1  = (const float*)d_in[11];
  float* out = (float*)d_out;
  char* ws = (char*)d_ws;

  u16* wx0 = (u16*)(ws + OFF_WX0);
  u16* wh0 = (u16*)(ws + OFF_WH0);
  u16* wx1 = (u16*)(ws + OFF_WX1);
  u16* wh1 = (u16*)(ws + OFF_WH1);
  u16* xin = (u16*)(ws + OFF_XIN);
  u16* xs1 = (u16*)(ws + OFF_XS1);
  u16* h1b = (u16*)(ws + OFF_H1B);
  float* pb0 = (float*)(ws + OFF_B0);
  float* pb1 = (float*)(ws + OFF_B1);
  unsigned* bar = (unsigned*)(ws + OFF_BAR);

  cvt_bf16<<<1024, 256, 0, stream>>>(Wih0, wx0, G4 * D / 4);
  cvt_bf16<<<1024, 256, 0, stream>>>(Whh0, wh0, G4 * H / 4);
  cvt_bf16<<<1024, 256, 0, stream>>>(Wih1, wx1, G4 * H / 4);
  cvt_bf16<<<1024, 256, 0, stream>>>(Whh1, wh1, G4 * H / 4);
  cvt_bf16<<<2048, 256, 0, stream>>>(input, xin, T * B * D / 4);
  init_state<<<512, 256, 0, stream>>>(h0, xs1, h1b, bih0, bhh0, bih1, bhh1, pb0, pb1, bar);
  lstm_seq<<<NBLK, NTHR, 0, stream>>>(xin, wx0, wh0, wx1, wh1, pb0, pb1,
                                      xs1, h1b, c0, reset, out, bar);
}

// Round 5
// 4563.342 us; speedup vs baseline: 3.6739x; 1.4378x over previous
//
#include <hip/hip_runtime.h>

typedef __bf16 bf16x8 __attribute__((ext_vector_type(8)));
typedef float f32x4 __attribute__((ext_vector_type(4)));
typedef unsigned u32x4 __attribute__((ext_vector_type(4)));
typedef unsigned short u16;
typedef unsigned long long u64;

constexpr int T = 256, B = 64, D = 512, H = 1024;
constexpr int G4 = 4 * H;
constexpr int NBLK = 128;   // 64 blocks layer0 + 64 blocks layer1 (1 block/CU)
constexpr int NTHR = 256;   // 4 waves; wave = one K-quarter, all 4 gates

// ---- workspace layout (bytes) ----
constexpr size_t OFF_WX0 = 0;                                   // Wih0 bf16 [4096][512]
constexpr size_t OFF_WH0 = OFF_WX0 + (size_t)G4 * D * 2;        // Whh0 bf16 [4096][1024]
constexpr size_t OFF_WX1 = OFF_WH0 + (size_t)G4 * H * 2;        // Wih1 bf16 [4096][1024]
constexpr size_t OFF_WH1 = OFF_WX1 + (size_t)G4 * H * 2;        // Whh1 bf16 [4096][1024]
constexpr size_t OFF_XIN = OFF_WH1 + (size_t)G4 * H * 2;        // input bf16 [T][B][D]
constexpr size_t OFF_XS1 = OFF_XIN + (size_t)T * B * D * 2;     // h0-out ring bf16 [4][B][H]
constexpr size_t OFF_H1B = OFF_XS1 + (size_t)4 * B * H * 2;     // h1 state bf16 [2][B][H]
constexpr size_t OFF_B0  = OFF_H1B + (size_t)2 * B * H * 2;     // bias0 f32 [4096]
constexpr size_t OFF_B1  = OFF_B0 + (size_t)G4 * 4;             // bias1 f32 [4096]
constexpr size_t OFF_BAR = OFF_B1 + (size_t)G4 * 4;             // barrier counter u32

__device__ __forceinline__ u16 f2bf(float f) {
  unsigned u = __builtin_bit_cast(unsigned, f);
  u += 0x7fffu + ((u >> 16) & 1u);
  return (u16)(u >> 16);
}

__device__ __forceinline__ f32x4 mfma16(bf16x8 a, bf16x8 b, f32x4 c) {
  return __builtin_amdgcn_mfma_f32_16x16x32_bf16(a, b, c, 0, 0, 0);
}

__device__ __forceinline__ float sigm(float x) { return 1.f / (1.f + expf(-x)); }

// ---------------- prep kernels ----------------
__global__ void cvt_bf16(const float* __restrict__ src, u16* __restrict__ dst, int n4) {
  int i = blockIdx.x * blockDim.x + threadIdx.x;
  int st = gridDim.x * blockDim.x;
  for (; i < n4; i += st) {
    float4 v = reinterpret_cast<const float4*>(src)[i];
    ushort4 o;
    o.x = f2bf(v.x); o.y = f2bf(v.y); o.z = f2bf(v.z); o.w = f2bf(v.w);
    reinterpret_cast<ushort4*>(dst)[i] = o;
  }
}

__global__ void init_state(const float* __restrict__ h0,
                           u16* __restrict__ xs1, u16* __restrict__ h1buf,
                           const float* __restrict__ bih0, const float* __restrict__ bhh0,
                           const float* __restrict__ bih1, const float* __restrict__ bhh1,
                           float* __restrict__ bias0, float* __restrict__ bias1,
                           unsigned* __restrict__ bar) {
  int i = blockIdx.x * blockDim.x + threadIdx.x;
  if (i == 0) *bar = 0u;
  if (i < 2 * B * H) {
    int l = i / (B * H), rem = i % (B * H);
    int b = rem / H, k = rem % H;
    u16 v = f2bf(h0[(size_t)b * 2 * H + (size_t)l * H + k]);
    if (l == 0) xs1[(size_t)b * H + k] = v;   // ring slot 0 = initial h for layer0
    else        h1buf[(size_t)b * H + k] = v; // parity 0 = initial h for layer1
  }
  if (i < G4) {
    bias0[i] = bih0[i] + bhh0[i];
    bias1[i] = bih1[i] + bhh1[i];
  }
}

// ---------------- persistent pipelined LSTM ----------------
// Per block: 16 h-columns, all 4 gates, all 64 batches.
// Wave ks (0..3) owns K-quarter; weights register-resident (192/256 VGPRs).
// Cross-block coherence: plain loads/stores + one agent fence pair per step.
template <int L>
__device__ __forceinline__ void run_layer(
    const u16* __restrict__ xin, const u16* __restrict__ wx, const u16* __restrict__ wh,
    const float* __restrict__ bias, u16* __restrict__ xs1, u16* __restrict__ h1b,
    const float* __restrict__ c0, const int* __restrict__ reset,
    float* __restrict__ out, unsigned* __restrict__ bar, int col0,
    f32x4* __restrict__ red, unsigned* __restrict__ rbits, float* __restrict__ lbias) {
  constexpr int KX  = L ? H : D;      // x-part K
  constexpr int NCX = KX / 32;        // x chunks (16 or 32)
  constexpr int NC  = NCX + H / 32;   // total K chunks (48 or 64)
  constexpr int NCW = NC / 4;         // chunks per wave (12 or 16)
  const size_t BH = (size_t)B * H;
  const size_t OUT_HN = (size_t)T * BH;
  const size_t OUT_CN = OUT_HN + 2 * BH;

  const int tid  = threadIdx.x;
  const int ks   = tid >> 6;          // wave = K-quarter
  const int lane = tid & 63;
  const int q    = lane >> 4;
  const int ln   = lane & 15;
  const int c0i  = ks * NCW;

  // ---- one-time LDS prep: packed reset bits + this block's bias rows
  for (int w = tid; w < 2 * T; w += NTHR) {
    const int t = w >> 1, half = (w & 1) * 32;
    unsigned v = 0;
#pragma unroll 8
    for (int i = 0; i < 32; ++i) v |= (unsigned)(reset[t * B + half + i] & 1) << i;
    rbits[w] = v;
  }
  if (tid < 64) lbias[tid] = bias[(tid >> 4) * H + col0 + (tid & 15)];

  // ---- preload this wave's weight fragments, PIN in regs (no launch-bound cap now)
  u32x4 wreg[4][NCW];
#pragma unroll
  for (int g = 0; g < 4; ++g)
#pragma unroll
    for (int cc = 0; cc < NCW; ++cc) {
      const int c = c0i + cc;
      const u16* W = (c < NCX) ? wx : wh;
      const int stride = (c < NCX) ? KX : H;
      const int kk = ((c < NCX) ? c : c - NCX) * 32 + q * 8;
      wreg[g][cc] = *reinterpret_cast<const u32x4*>(
          W + (size_t)(g * H + col0 + ln) * stride + kk);
    }
#pragma unroll
  for (int g = 0; g < 4; ++g)
#pragma unroll
    for (int cc = 0; cc < NCW; ++cc)
      asm volatile("" : "+v"(wreg[g][cc]));   // opaque: no remat, must stay in regs

  // ---- cell-update state: thread owns one acc-quad = batches b0..b0+3, col cl
  const int b0 = (tid >> 4) * 4;
  const int cl = col0 + (tid & 15);
  float creg[4];
#pragma unroll
  for (int r = 0; r < 4; ++r)
    creg[r] = c0[(size_t)(b0 + r) * 2 * H + (size_t)L * H + cl];

  __syncthreads();
  float bval[4];
#pragma unroll
  for (int g = 0; g < 4; ++g) bval[g] = lbias[g * 16 + (tid & 15)];

  for (int s = 0; s <= T; ++s) {
    const bool active = (L == 0) ? (s < T) : (s >= 1);
    if (active) {
      const int t = (L == 0) ? s : s - 1;

      f32x4 acc[4][4];
#pragma unroll
      for (int g = 0; g < 4; ++g)
#pragma unroll
        for (int m = 0; m < 4; ++m) acc[g][m] = (f32x4){0.f, 0.f, 0.f, 0.f};

      const unsigned rw0 = rbits[2 * t], rw1 = rbits[2 * t + 1];
      const int rz[4] = {(int)((rw0 >> ln) & 1u), (int)((rw0 >> (16 + ln)) & 1u),
                         (int)((rw1 >> ln) & 1u), (int)((rw1 >> (16 + ln)) & 1u)};

      const u16* xsrc;
      if constexpr (L == 0) xsrc = xin + (size_t)t * B * D;
      else                  xsrc = xs1 + (size_t)((t + 1) & 3) * BH;
      const u16* hsrc = (L == 0) ? xs1 + (size_t)(t & 3) * BH
                                 : h1b + (size_t)(t & 1) * BH;

#pragma unroll
      for (int cc = 0; cc < NCW; ++cc) {
        const int c = c0i + cc;
        uint4 f[4];
        if (c < NCX) {                      // x part (no reset gating)
          const int kk = c * 32 + q * 8;
#pragma unroll
          for (int m = 0; m < 4; ++m)
            f[m] = *reinterpret_cast<const uint4*>(xsrc + (size_t)(16 * m + ln) * KX + kk);
        } else {                            // h part (reset zeroes state)
          const int kk = (c - NCX) * 32 + q * 8;
#pragma unroll
          for (int m = 0; m < 4; ++m) {
            uint4 v = *reinterpret_cast<const uint4*>(hsrc + (size_t)(16 * m + ln) * H + kk);
            f[m] = rz[m] ? make_uint4(0u, 0u, 0u, 0u) : v;
          }
        }
#pragma unroll
        for (int g = 0; g < 4; ++g)
#pragma unroll
          for (int m = 0; m < 4; ++m)
            acc[g][m] = mfma16(__builtin_bit_cast(bf16x8, f[m]),
                               __builtin_bit_cast(bf16x8, wreg[g][cc]), acc[g][m]);
      }

      // ---- dump partials: lane-consecutive f32x4 -> conflict-free ds_write_b128
#pragma unroll
      for (int g = 0; g < 4; ++g)
#pragma unroll
        for (int m = 0; m < 4; ++m)
          red[(g * 4 + ks) * 256 + m * 64 + q * 16 + ln] = acc[g][m];
      __syncthreads();

      // ---- reduce + cell update: thread tid owns cells (b0..b0+3, col cl)
      {
        f32x4 gate[4];
#pragma unroll
        for (int g = 0; g < 4; ++g) {
          f32x4 sum = red[(g * 4 + 0) * 256 + tid];
#pragma unroll
          for (int w = 1; w < 4; ++w) sum += red[(g * 4 + w) * 256 + tid];
          gate[g] = sum + (f32x4){bval[g], bval[g], bval[g], bval[g]};
        }
        const unsigned rstw = rbits[2 * t + (b0 >> 5)] >> (b0 & 31);
        float hv[4];
        u16 hb[4];
#pragma unroll
        for (int r = 0; r < 4; ++r) {
          float cp = ((rstw >> r) & 1u) ? 0.f : creg[r];
          float i_ = sigm(gate[0][r]);
          float f_ = sigm(gate[1][r]);
          float g_ = tanhf(gate[2][r]);
          float o_ = sigm(gate[3][r]);
          float cn = fmaf(f_, cp, i_ * g_);
          float hn = o_ * tanhf(cn);
          creg[r] = cn;
          hv[r] = hn;
          hb[r] = f2bf(hn);
        }
        u16* hdst = (L == 0)
            ? xs1 + (size_t)((t + 1) & 3) * BH
            : h1b + (size_t)((t + 1) & 1) * BH;
#pragma unroll
        for (int r = 0; r < 4; ++r)
          hdst[(size_t)(b0 + r) * H + cl] = hb[r];          // plain store; wbl2 publishes
        if constexpr (L == 1) {
#pragma unroll
          for (int r = 0; r < 4; ++r)
            __builtin_nontemporal_store(hv[r], &out[(size_t)t * BH + (size_t)(b0 + r) * H + cl]);
        }
        if (t == T - 1) {
#pragma unroll
          for (int r = 0; r < 4; ++r) {
            __builtin_nontemporal_store(
                hv[r], &out[OUT_HN + (size_t)(b0 + r) * 2 * H + (size_t)L * H + cl]);
            __builtin_nontemporal_store(
                creg[r], &out[OUT_CN + (size_t)(b0 + r) * 2 * H + (size_t)L * H + cl]);
          }
        }
      }
    }

    // ---- grid barrier: release(wbl2) -> add -> relaxed spin -> acquire(inv)
    if (s < T) {
      __syncthreads();   // drains vmcnt: all block stores are at L2
      if (tid == 0) {
        __builtin_amdgcn_fence(__ATOMIC_RELEASE, "agent");   // buffer_wbl2: L2 -> LLC
        __hip_atomic_fetch_add(bar, 1u, __ATOMIC_RELAXED, __HIP_MEMORY_SCOPE_AGENT);
        const unsigned target = (unsigned)(s + 1) * NBLK;
        while (__hip_atomic_load(bar, __ATOMIC_RELAXED, __HIP_MEMORY_SCOPE_AGENT) < target)
          __builtin_amdgcn_s_sleep(2);
        __builtin_amdgcn_fence(__ATOMIC_ACQUIRE, "agent");   // buffer_inv: L1+L2 refresh
      }
      __syncthreads();
    }
  }
}

__global__ void __launch_bounds__(NTHR, 1) lstm_seq(
    const u16* __restrict__ xin,
    const u16* __restrict__ wx0, const u16* __restrict__ wh0,
    const u16* __restrict__ wx1, const u16* __restrict__ wh1,
    const float* __restrict__ bias0, const float* __restrict__ bias1,
    u16* __restrict__ xs1, u16* __restrict__ h1b,
    const float* __restrict__ c0, const int* __restrict__ reset,
    float* __restrict__ out, unsigned* __restrict__ bar) {
  __shared__ f32x4 red[4 * 4 * 256];      // 64 KB partials
  __shared__ unsigned rbits[2 * T];       // 2 KB packed reset bits
  __shared__ float lbias[64];             // this block's 64 bias rows
  const int group = blockIdx.x >> 6;
  const int col0 = (blockIdx.x & 63) << 4;
  if (group == 0)
    run_layer<0>(xin, wx0, wh0, bias0, xs1, h1b, c0, reset, out, bar, col0, red, rbits, lbias);
  else
    run_layer<1>(nullptr, wx1, wh1, bias1, xs1, h1b, c0, reset, out, bar, col0, red, rbits, lbias);
}

extern "C" void kernel_launch(void* const* d_in, const int* in_sizes, int n_in,
                              void* d_out, int out_size, void* d_ws, size_t ws_size,
                              hipStream_t stream) {
  (void)in_sizes; (void)n_in; (void)out_size; (void)ws_size;
  const float* input = (const float*)d_in[0];
  const int*   reset = (const int*)d_in[1];
  const float* h0    = (const float*)d_in[2];
  const float* c0    = (const float*)d_in[3];
  const float* Wih0  = (const float*)d_in[4];
  const float* Whh0  = (const float*)d_in[5];
  const float* bih0  = (const float*)d_in[6];
  const float* bhh0  = (const float*)d_in[7];
  const float* Wih1  = (const float*)d_in[8];
  const float* Whh1  = (const float*)d_in[9];
  const float* bih1  = (const float*)d_in[10];
  const float* bhh1  = (const float*)d_in[11];
  float* out = (float*)d_out;
  char* ws = (char*)d_ws;

  u16* wx0 = (u16*)(ws + OFF_WX0);
  u16* wh0 = (u16*)(ws + OFF_WH0);
  u16* wx1 = (u16*)(ws + OFF_WX1);
  u16* wh1 = (u16*)(ws + OFF_WH1);
  u16* xin = (u16*)(ws + OFF_XIN);
  u16* xs1 = (u16*)(ws + OFF_XS1);
  u16* h1b = (u16*)(ws + OFF_H1B);
  float* pb0 = (float*)(ws + OFF_B0);
  float* pb1 = (float*)(ws + OFF_B1);
  unsigned* bar = (unsigned*)(ws + OFF_BAR);

  cvt_bf16<<<1024, 256, 0, stream>>>(Wih0, wx0, G4 * D / 4);
  cvt_bf16<<<1024, 256, 0, stream>>>(Whh0, wh0, G4 * H / 4);
  cvt_bf16<<<1024, 256, 0, stream>>>(Wih1, wx1, G4 * H / 4);
  cvt_bf16<<<1024, 256, 0, stream>>>(Whh1, wh1, G4 * H / 4);
  cvt_bf16<<<2048, 256, 0, stream>>>(input, xin, T * B * D / 4);
  init_state<<<512, 256, 0, stream>>>(h0, xs1, h1b, bih0, bhh0, bih1, bhh1, pb0, pb1, bar);
  lstm_seq<<<NBLK, NTHR, 0, stream>>>(xin, wx0, wh0, wx1, wh1, pb0, pb1,
                                      xs1, h1b, c0, reset, out, bar);
}